// Round 2
// baseline (148.474 us; speedup 1.0000x reference)
//
#include <hip/hip_runtime.h>
#include <hip/hip_bf16.h>

// Problem constants
#define NNv   40
#define MMv   40
#define OOv   200
#define KKv   1600            // NN*MM
#define OPAD  208             // 13 col-tiles of 16
#define NSTEPS 50             // KK / 32
#define CHUNK_BYTES 13312     // OPAD * 4 slots * 16 B  (one K=32 chunk of W-bf16)
#define PADR  44              // fp32 row stride for x/y tiles in LDS (2-way banks = free)

typedef __attribute__((ext_vector_type(8))) short short8;
typedef __attribute__((ext_vector_type(4))) float floatx4;
typedef __attribute__((ext_vector_type(4))) unsigned int uintx4;

// ---------------------------------------------------------------------------
// Pre-kernel: W [200][1600] fp32 -> Wb bf16, K-chunk-major, no swizzle.
// Wb bf16 index: idx = c*(OPAD*4*8) + (o*4 + kg)*8 + j ; k = c*32 + kg*8 + j
// ---------------------------------------------------------------------------
__global__ void wb_convert_kernel(const float* __restrict__ W,
                                  unsigned short* __restrict__ Wb) {
    int idx = blockIdx.x * 256 + threadIdx.x;
    if (idx >= NSTEPS * OPAD * 32) return;     // 332800
    int j    = idx & 7;
    int slot = (idx >> 3) % (OPAD * 4);
    int c    = (idx >> 3) / (OPAD * 4);
    int o    = slot >> 2;
    int kg   = slot & 3;
    int k    = c * 32 + kg * 8 + j;
    float v  = (o < OOv) ? W[o * KKv + k] : 0.0f;
    __hip_bfloat16 h = __float2bfloat16(v);
    Wb[idx] = *reinterpret_cast<unsigned short*>(&h);
}

__device__ __forceinline__ unsigned int cvt2(float a, float b) {
    __hip_bfloat162 h = __float22bfloat162_rn(float2{a, b});
    union { __hip_bfloat162 h2; unsigned int u; } cv;
    cv.h2 = h;
    return cv.u;
}

// ---------------------------------------------------------------------------
// Main kernel: 512 blocks x 256 threads. Block = 128 rows x 208 cols.
// B fragments come straight from L2 (global->VGPR, 1-chunk register prefetch).
// K-loop is barrier-free; only barrier is after the x/y prologue stage.
// ---------------------------------------------------------------------------
__global__ __launch_bounds__(256, 2) void cin_mfma_kernel(
        const float* __restrict__ X, const float* __restrict__ Y,
        const unsigned short* __restrict__ Wb, float* __restrict__ Out) {
    __shared__ __align__(16) float xlds[128 * PADR];
    __shared__ __align__(16) float ylds[128 * PADR];

    const int tid     = threadIdx.x;
    const int wave    = tid >> 6;
    const int lane    = tid & 63;
    const int li      = lane & 15;
    const int kg      = lane >> 4;
    const int rowhalf = wave & 1;
    const int colgrp  = wave >> 1;
    const int ntiles  = colgrp ? 6 : 7;
    const int obase   = colgrp * 112;
    const long blockbase = (long)blockIdx.x * 128;

    // ---- prologue: stage x,y tiles (128 rows x 40 fp32 each, contiguous)
    const float* xg = X + blockbase * NNv;
    const float* yg = Y + blockbase * MMv;
    for (int i = tid; i < 1280; i += 256) {      // 1280 float4s = 5120 floats
        int r  = i / 10;
        int c4 = (i % 10) * 4;                   // 40 % 4 == 0: never crosses a row
        floatx4 vx = *(const floatx4*)(xg + i * 4);
        *(floatx4*)(xlds + r * PADR + c4) = vx;
        floatx4 vy = *(const floatx4*)(yg + i * 4);
        *(floatx4*)(ylds + r * PADR + c4) = vy;
    }
    __syncthreads();

    floatx4 acc[4][7];
#pragma unroll
    for (int rt = 0; rt < 4; ++rt)
#pragma unroll
        for (int ct = 0; ct < 7; ++ct)
            acc[rt][ct] = (floatx4){0.f, 0.f, 0.f, 0.f};

    // per-lane incremental k decomposition: k = step*32 + kg*8 (+j); s=k%40, n=k/40
    int s = kg * 8;
    int n = 0;
    const int rowb = rowhalf * 64 + li;

    // per-lane B pointer: frag(ct) at bptr + ct*1024; next chunk at +CHUNK_BYTES
    const char* bptr = (const char*)Wb + (obase + li) * 64 + kg * 16;

    short8 b0[7], b1[7];
#pragma unroll
    for (int ct = 0; ct < 7; ++ct)
        if (ct < ntiles) b0[ct] = *(const short8*)(bptr + ct * 1024);

    auto compute = [&](short8 (&bf)[7]) {
        short8 af[4];
#pragma unroll
        for (int rt = 0; rt < 4; ++rt) {
            int row = rowb + rt * 16;
            float xv = xlds[row * PADR + n];
            floatx4 y0 = *(const floatx4*)(ylds + row * PADR + s);
            floatx4 y1 = *(const floatx4*)(ylds + row * PADR + s + 4);
            union { short8 s8; uintx4 u4; } a;
            a.u4[0] = cvt2(xv * y0.x, xv * y0.y);
            a.u4[1] = cvt2(xv * y0.z, xv * y0.w);
            a.u4[2] = cvt2(xv * y1.x, xv * y1.y);
            a.u4[3] = cvt2(xv * y1.z, xv * y1.w);
            af[rt] = a.s8;
        }
#pragma unroll
        for (int ct = 0; ct < 7; ++ct)
            if (ct < ntiles)
#pragma unroll
                for (int rt = 0; rt < 4; ++rt)
                    acc[rt][ct] = __builtin_amdgcn_mfma_f32_16x16x32_bf16(
                        af[rt], bf[ct], acc[rt][ct], 0, 0, 0);
        s += 32;
        if (s >= 40) { s -= 40; ++n; }
    };

#pragma unroll 1
    for (int step = 0; step < NSTEPS; step += 2) {
        if (step + 1 < NSTEPS) {
#pragma unroll
            for (int ct = 0; ct < 7; ++ct)
                if (ct < ntiles)
                    b1[ct] = *(const short8*)(bptr + CHUNK_BYTES + ct * 1024);
        }
        compute(b0);
        if (step + 2 < NSTEPS) {
#pragma unroll
            for (int ct = 0; ct < 7; ++ct)
                if (ct < ntiles)
                    b0[ct] = *(const short8*)(bptr + 2 * CHUNK_BYTES + ct * 1024);
        }
        if (step + 1 < NSTEPS) compute(b1);
        bptr += 2 * CHUNK_BYTES;
    }

    // ---- epilogue: C/D layout col = lane&15, row = (lane>>4)*4 + reg  [m89]
#pragma unroll
    for (int rt = 0; rt < 4; ++rt) {
#pragma unroll
        for (int ct = 0; ct < 7; ++ct) {
            if (ct >= ntiles) continue;
            int gcol = obase + ct * 16 + li;
            if (gcol < OOv) {
#pragma unroll
                for (int r4 = 0; r4 < 4; ++r4) {
                    long grow = blockbase + rowhalf * 64 + rt * 16 + kg * 4 + r4;
                    Out[grow * OOv + gcol] = acc[rt][ct][r4];
                }
            }
        }
    }
}

extern "C" void kernel_launch(void* const* d_in, const int* in_sizes, int n_in,
                              void* d_out, int out_size, void* d_ws, size_t ws_size,
                              hipStream_t stream) {
    (void)in_sizes; (void)n_in; (void)out_size; (void)ws_size;
    const float* X = (const float*)d_in[0];
    const float* Y = (const float*)d_in[1];
    const float* W = (const float*)d_in[2];
    float* Out = (float*)d_out;
    unsigned short* Wb = (unsigned short*)d_ws;   // 665,600 B of scratch

    wb_convert_kernel<<<1300, 256, 0, stream>>>(W, Wb);
    cin_mfma_kernel<<<512, 256, 0, stream>>>(X, Y, Wb, Out);
}